// Round 1
// baseline (710.542 us; speedup 1.0000x reference)
//
#include <hip/hip_runtime.h>
#include <hip/hip_bf16.h>

// Problem constants (B, D, H, W) = (8, 128, 64, 64)
#define B_   8
#define D_   128
#define N_   4096
#define CH   (2 * D_ + 3)   // 259 output channels
#define DPAD 144            // v1 channels padded to MFMA multiple: 128 v1 + 2 grid + 14 zero
#define XS   68             // LDS x-tile row stride in floats (16B-aligned rows, conflict-friendly)

typedef short bf8 __attribute__((ext_vector_type(8)));   // 8 bf16 = 4 VGPRs (MFMA A/B frag)
typedef float f4  __attribute__((ext_vector_type(4)));   // MFMA C/D frag

__device__ __forceinline__ unsigned short f2bf(float x) {
    // round-to-nearest-even float -> bf16 (bit trick; inputs are finite here)
    unsigned int u = __float_as_uint(x);
    return (unsigned short)((u + 0x7FFFu + ((u >> 16) & 1u)) >> 16);
}

// ---------------------------------------------------------------------------
// Kernel 1: transpose Wq/Wk/Wv (128x128) so projection reads are W^T[d][o]
// (wave-uniform contiguous scalar loads in the proj inner loop).
// ---------------------------------------------------------------------------
__global__ void wtrans_kernel(const float* __restrict__ Wq,
                              const float* __restrict__ Wk,
                              const float* __restrict__ Wv,
                              float* __restrict__ WT) {
    const float* src = (blockIdx.x == 0) ? Wq : (blockIdx.x == 1) ? Wk : Wv;
    float* dst = WT + (size_t)blockIdx.x * D_ * D_;
    for (int idx = threadIdx.x; idx < D_ * D_; idx += blockDim.x) {
        int o = idx >> 7, d = idx & 127;
        dst[d * D_ + o] = src[idx];
    }
}

// ---------------------------------------------------------------------------
// Kernel 2: projections + residual + L2 norm.
//   q = Wq x0 + x0  -> normalize -> Qh  bf16 [b][n][128]
//   k = Wk x1 + x1  -> normalize -> Kh  bf16 [b][m][128]
//   v1 = Wv x1 + x1 ->              V1T bf16 [b][144][m]  (rows 128/129 = grid, 130..143 = 0)
//   v0 = Wv x0 + x0 -> fp32 directly to out channels 0..127
// Block: (b, 64-column chunk), 256 threads. Thread t owns column n = t&63 and
// 32 output channels o0..o0+31, o0 = (t>>6)*32 (wave-uniform -> scalar W loads).
// ---------------------------------------------------------------------------
__global__ __launch_bounds__(256) void proj_kernel(
    const float* __restrict__ vol0, const float* __restrict__ vol1,
    const float* __restrict__ WT, float* __restrict__ out,
    unsigned short* __restrict__ Qh, unsigned short* __restrict__ Kh,
    unsigned short* __restrict__ V1T)
{
    __shared__ float x0t[D_ * XS];
    __shared__ float x1t[D_ * XS];
    __shared__ float normp[4][64];

    const int tid = threadIdx.x;
    const int b   = blockIdx.y;
    const int n0  = blockIdx.x * 64;

    // stage x tiles: [128 ch][64 cols]
    for (int idx = tid; idx < D_ * 16; idx += 256) {
        int row = idx >> 4, c4 = (idx & 15) * 4;
        float4 a = *(const float4*)(vol0 + ((size_t)(b * D_ + row)) * N_ + n0 + c4);
        float4 c = *(const float4*)(vol1 + ((size_t)(b * D_ + row)) * N_ + n0 + c4);
        *(float4*)(x0t + row * XS + c4) = a;
        *(float4*)(x1t + row * XS + c4) = c;
    }
    __syncthreads();

    const int n  = tid & 63;
    const int og = tid >> 6;
    const int o0 = __builtin_amdgcn_readfirstlane(og * 32);  // force SGPR -> scalar W loads

    const float* WqT = WT;
    const float* WkT = WT + D_ * D_;
    const float* WvT = WT + 2 * D_ * D_;

    float acc[32];

    auto matmul = [&](const float* Wt, const float* xt) {
        #pragma unroll
        for (int j = 0; j < 32; ++j) acc[j] = 0.f;
        for (int d = 0; d < D_; ++d) {
            float xv = xt[d * XS + n];
            const float* wrow = Wt + d * D_ + o0;   // 32 consecutive floats, wave-uniform
            #pragma unroll
            for (int j = 0; j < 32; ++j) acc[j] = fmaf(wrow[j], xv, acc[j]);
        }
        #pragma unroll
        for (int j = 0; j < 32; ++j) acc[j] += xt[(o0 + j) * XS + n];  // residual
    };

    auto l2norm_inv = [&]() -> float {
        float ss = 0.f;
        #pragma unroll
        for (int j = 0; j < 32; ++j) ss = fmaf(acc[j], acc[j], ss);
        __syncthreads();                 // protect normp reuse across sections
        normp[og][n] = ss;
        __syncthreads();
        float nrm = sqrtf(normp[0][n] + normp[1][n] + normp[2][n] + normp[3][n]);
        return 1.f / fmaxf(nrm, 1e-12f);
    };

    auto store_bf16 = [&](unsigned short* dstbase, float scale) {
        unsigned int pk[16];
        #pragma unroll
        for (int j = 0; j < 16; ++j)
            pk[j] = (unsigned int)f2bf(acc[2 * j] * scale) |
                    ((unsigned int)f2bf(acc[2 * j + 1] * scale) << 16);
        uint4* dst = (uint4*)(dstbase + ((size_t)(n0 + n)) * D_ + o0);
        dst[0] = make_uint4(pk[0],  pk[1],  pk[2],  pk[3]);
        dst[1] = make_uint4(pk[4],  pk[5],  pk[6],  pk[7]);
        dst[2] = make_uint4(pk[8],  pk[9],  pk[10], pk[11]);
        dst[3] = make_uint4(pk[12], pk[13], pk[14], pk[15]);
    };

    auto spill_to = [&](float* xt) {      // regs -> LDS (transposed) for coalesced writeback
        __syncthreads();                  // everyone done READING xt
        #pragma unroll
        for (int j = 0; j < 32; ++j) xt[(o0 + j) * XS + n] = acc[j];
        __syncthreads();
    };

    // ---- Q ----
    matmul(WqT, x0t);
    { float r = l2norm_inv(); store_bf16(Qh + (size_t)b * N_ * D_, r); }
    // ---- K ----
    matmul(WkT, x1t);
    { float r = l2norm_inv(); store_bf16(Kh + (size_t)b * N_ * D_, r); }
    // ---- V1 -> V1T bf16 [b][144][m] ----
    matmul(WvT, x1t);
    spill_to(x1t);
    for (int idx = tid; idx < D_ * 8; idx += 256) {
        int row = idx >> 3, c8 = (idx & 7) * 8;
        const float* src = x1t + row * XS + c8;
        unsigned int w0 = f2bf(src[0]) | ((unsigned int)f2bf(src[1]) << 16);
        unsigned int w1 = f2bf(src[2]) | ((unsigned int)f2bf(src[3]) << 16);
        unsigned int w2 = f2bf(src[4]) | ((unsigned int)f2bf(src[5]) << 16);
        unsigned int w3 = f2bf(src[6]) | ((unsigned int)f2bf(src[7]) << 16);
        *(uint4*)(V1T + (size_t)(b * DPAD + row) * N_ + n0 + c8) = make_uint4(w0, w1, w2, w3);
    }
    // grid rows (128 = u[m/64], 129 = v[m%64]) + zero padding rows
    for (int idx = tid; idx < 16 * 64; idx += 256) {
        int row = 128 + (idx >> 6), col = idx & 63;
        int m = n0 + col;
        float val = 0.f;
        if (row == 128) val = -1.f + (2.f / 63.f) * (float)(m >> 6);
        else if (row == 129) val = -1.f + (2.f / 63.f) * (float)(m & 63);
        V1T[(size_t)(b * DPAD + row) * N_ + m] = f2bf(val);
    }
    // ---- V0 -> out channels 0..127 (fp32) ----
    matmul(WvT, x0t);
    spill_to(x0t);
    for (int idx = tid; idx < D_ * 16; idx += 256) {
        int row = idx >> 4, c4 = (idx & 15) * 4;
        const float* src = x0t + row * XS + c4;
        float4 v; v.x = src[0]; v.y = src[1]; v.z = src[2]; v.w = src[3];
        *(float4*)(out + ((size_t)(b * CH + row)) * N_ + n0 + c4) = v;
    }
}

// ---------------------------------------------------------------------------
// Kernel 3: full attention per (b, 64 q-rows). 4 waves, wave owns 16 q-rows.
// Scores are bounded (|q.k| <= ~1.01, q/k unit vectors) -> NO online softmax:
//   p = exp(s) unnormalized, per-lane running sum l and running max M,
//   out = acc/l at the end, max_score = exp(M)/l.
// Per 32-m chunk: 8 QK MFMAs + exp + bf16 P via per-wave LDS (double-buffered,
// one barrier per chunk) + 9 PV MFMAs over 144 padded V channels.
// ---------------------------------------------------------------------------
__global__ __launch_bounds__(256) void attn_kernel(
    const unsigned short* __restrict__ Qh, const unsigned short* __restrict__ Kh,
    const unsigned short* __restrict__ V1T, float* __restrict__ out)
{
    __shared__ unsigned short Pt[2][4][16 * 40];   // [dbuf][wave][16 rows x 40 stride]
    __shared__ float otile[DPAD * 68];             // epilogue transpose tile
    __shared__ float maxrow[64];

    const int tid  = threadIdx.x;
    const int wave = tid >> 6, lane = tid & 63;
    const int l15  = lane & 15, lh = lane >> 4;
    const int b    = blockIdx.y;
    const int nb0  = blockIdx.x * 64;
    const int n0   = nb0 + wave * 16;

    // Q fragments (A-operand): lane holds q[n0 + l15][dc*32 + lh*8 + j]
    bf8 qf[4];
    const unsigned short* qp = Qh + ((size_t)(b * N_ + n0 + l15)) * D_ + lh * 8;
    #pragma unroll
    for (int dc = 0; dc < 4; ++dc) qf[dc] = *(const bf8*)(qp + dc * 32);

    f4 acc[9];
    #pragma unroll
    for (int dc = 0; dc < 9; ++dc) acc[dc] = (f4){0.f, 0.f, 0.f, 0.f};
    float Mp[4] = {-1e30f, -1e30f, -1e30f, -1e30f};
    float lp[4] = {0.f, 0.f, 0.f, 0.f};

    const unsigned short* Kb = Kh + (size_t)b * N_ * D_;
    const unsigned short* Vb = V1T + (size_t)b * DPAD * N_;
    unsigned short* PwA = &Pt[0][wave][0];
    unsigned short* PwB = &Pt[1][wave][0];

    for (int m0 = 0, it = 0; m0 < N_; m0 += 32, ++it) {
        unsigned short* Pw = (it & 1) ? PwB : PwA;
        f4 s0 = (f4){0.f, 0.f, 0.f, 0.f};
        f4 s1 = (f4){0.f, 0.f, 0.f, 0.f};
        // QK^T: S[n][m] tile 16x32 (two 16-col fragments)
        const unsigned short* kp0 = Kb + ((size_t)(m0 + l15)) * D_ + lh * 8;
        #pragma unroll
        for (int dc = 0; dc < 4; ++dc) {
            bf8 kf = *(const bf8*)(kp0 + dc * 32);
            s0 = __builtin_amdgcn_mfma_f32_16x16x32_bf16(qf[dc], kf, s0, 0, 0, 0);
        }
        const unsigned short* kp1 = kp0 + 16 * D_;
        #pragma unroll
        for (int dc = 0; dc < 4; ++dc) {
            bf8 kf = *(const bf8*)(kp1 + dc * 32);
            s1 = __builtin_amdgcn_mfma_f32_16x16x32_bf16(qf[dc], kf, s1, 0, 0, 0);
        }
        // bounded-score softmax-lite; C layout: row n0+lh*4+r, col m0+l15 (+16)
        #pragma unroll
        for (int r = 0; r < 4; ++r) {
            float sv0 = s0[r], sv1 = s1[r];
            Mp[r] = fmaxf(Mp[r], fmaxf(sv0, sv1));
            float p0 = __expf(sv0), p1 = __expf(sv1);
            lp[r] += p0 + p1;
            Pw[(lh * 4 + r) * 40 + l15]      = f2bf(p0);
            Pw[(lh * 4 + r) * 40 + 16 + l15] = f2bf(p1);
        }
        __syncthreads();   // orders P write -> P read (drains lgkm); dbuf handles WAR
        // PV: A = P[16n x 32m] from LDS, B = V1T rows (contiguous along m)
        bf8 pf = *(const bf8*)(Pw + l15 * 40 + lh * 8);
        const unsigned short* vp = Vb + (size_t)l15 * N_ + m0 + lh * 8;
        #pragma unroll
        for (int dc = 0; dc < 9; ++dc) {
            bf8 vf = *(const bf8*)(vp + (size_t)dc * 16 * N_);
            acc[dc] = __builtin_amdgcn_mfma_f32_16x16x32_bf16(pf, vf, acc[dc], 0, 0, 0);
        }
    }

    // reduce row stats across the 16-lane group that shares each row
    #pragma unroll
    for (int off = 1; off < 16; off <<= 1) {
        #pragma unroll
        for (int r = 0; r < 4; ++r) {
            Mp[r] = fmaxf(Mp[r], __shfl_xor(Mp[r], off, 64));
            lp[r] += __shfl_xor(lp[r], off, 64);
        }
    }
    float rl[4];
    #pragma unroll
    for (int r = 0; r < 4; ++r) rl[r] = 1.f / lp[r];

    // epilogue: transpose through LDS for coalesced channel-major stores
    #pragma unroll
    for (int dc = 0; dc < 9; ++dc) {
        #pragma unroll
        for (int r = 0; r < 4; ++r)
            otile[(dc * 16 + l15) * 68 + wave * 16 + lh * 4 + r] = acc[dc][r] * rl[r];
    }
    if (l15 == 0) {
        #pragma unroll
        for (int r = 0; r < 4; ++r)
            maxrow[wave * 16 + lh * 4 + r] = __expf(Mp[r]) * rl[r];
    }
    __syncthreads();
    for (int idx = tid; idx < 130 * 16; idx += 256) {
        int row = idx >> 4, c4 = (idx & 15) * 4;
        int ch = (row < 128) ? (128 + row) : (256 + (row - 128));
        const float* src = otile + row * 68 + c4;
        float4 v; v.x = src[0]; v.y = src[1]; v.z = src[2]; v.w = src[3];
        *(float4*)(out + ((size_t)(b * CH + ch)) * N_ + nb0 + c4) = v;
    }
    if (tid < 16) {
        float4 v;
        v.x = maxrow[tid * 4]; v.y = maxrow[tid * 4 + 1];
        v.z = maxrow[tid * 4 + 2]; v.w = maxrow[tid * 4 + 3];
        *(float4*)(out + ((size_t)(b * CH + 258)) * N_ + nb0 + tid * 4) = v;
    }
}

// ---------------------------------------------------------------------------
extern "C" void kernel_launch(void* const* d_in, const int* in_sizes, int n_in,
                              void* d_out, int out_size, void* d_ws, size_t ws_size,
                              hipStream_t stream) {
    const float* vol0 = (const float*)d_in[0];
    const float* vol1 = (const float*)d_in[1];
    const float* Wq   = (const float*)d_in[2];
    const float* Wk   = (const float*)d_in[3];
    const float* Wv   = (const float*)d_in[4];
    float* out = (float*)d_out;

    char* ws = (char*)d_ws;
    const size_t QH_BYTES  = (size_t)B_ * N_ * D_ * 2;        // 8 MiB
    const size_t V1T_BYTES = (size_t)B_ * DPAD * N_ * 2;      // 9 MiB
    unsigned short* Qh  = (unsigned short*)(ws);
    unsigned short* Kh  = (unsigned short*)(ws + QH_BYTES);
    unsigned short* V1T = (unsigned short*)(ws + 2 * QH_BYTES);
    float* WT = (float*)(ws + 2 * QH_BYTES + V1T_BYTES);      // 3 * 128 * 128 fp32

    hipLaunchKernelGGL(wtrans_kernel, dim3(3), dim3(256), 0, stream, Wq, Wk, Wv, WT);
    hipLaunchKernelGGL(proj_kernel, dim3(64, B_), dim3(256), 0, stream,
                       vol0, vol1, WT, out, Qh, Kh, V1T);
    hipLaunchKernelGGL(attn_kernel, dim3(64, B_), dim3(256), 0, stream,
                       Qh, Kh, V1T, out);
}

// Round 2
// 228.511 us; speedup vs baseline: 3.1094x; 3.1094x over previous
//
#include <hip/hip_runtime.h>
#include <hip/hip_bf16.h>

// Problem constants (B, D, H, W) = (8, 128, 64, 64)
#define B_   8
#define D_   128
#define N_   4096
#define CH   (2 * D_ + 3)   // 259 output channels
#define DPAD 144            // v1 channels padded: 128 v1 + 2 grid + row130=ones + zeros
#define XS   68             // proj LDS x-tile row stride in floats

typedef short bf8 __attribute__((ext_vector_type(8)));   // 8 bf16 = 4 VGPRs (MFMA A/B frag)
typedef float f4  __attribute__((ext_vector_type(4)));   // MFMA C/D frag

typedef unsigned int as1_u32 __attribute__((address_space(1)));
typedef unsigned int as3_u32 __attribute__((address_space(3)));

__device__ __forceinline__ void gll16(const void* g, void* l) {
    // async global->LDS, 16B per lane; LDS dest = wave-uniform base + lane*16
    __builtin_amdgcn_global_load_lds((as1_u32*)(unsigned long long)g,
                                     (as3_u32*)(unsigned int)(unsigned long long)l,
                                     16, 0, 0);
}

__device__ __forceinline__ unsigned short f2bf(float x) {
    unsigned int u = __float_as_uint(x);
    return (unsigned short)((u + 0x7FFFu + ((u >> 16) & 1u)) >> 16);
}

// ---------------------------------------------------------------------------
// Kernel 1: transpose Wq/Wk/Wv
// ---------------------------------------------------------------------------
__global__ void wtrans_kernel(const float* __restrict__ Wq,
                              const float* __restrict__ Wk,
                              const float* __restrict__ Wv,
                              float* __restrict__ WT) {
    const float* src = (blockIdx.x == 0) ? Wq : (blockIdx.x == 1) ? Wk : Wv;
    float* dst = WT + (size_t)blockIdx.x * D_ * D_;
    for (int idx = threadIdx.x; idx < D_ * D_; idx += blockDim.x) {
        int o = idx >> 7, d = idx & 127;
        dst[d * D_ + o] = src[idx];
    }
}

// ---------------------------------------------------------------------------
// Kernel 2: projections + residual + L2 norm.
//   Qh gets an extra log2(e) factor folded in (attn uses exp2).
//   V1T row 130 = 1.0 -> PV MFMA produces the softmax denominator for free.
// ---------------------------------------------------------------------------
__global__ __launch_bounds__(256) void proj_kernel(
    const float* __restrict__ vol0, const float* __restrict__ vol1,
    const float* __restrict__ WT, float* __restrict__ out,
    unsigned short* __restrict__ Qh, unsigned short* __restrict__ Kh,
    unsigned short* __restrict__ V1T)
{
    __shared__ float x0t[D_ * XS];
    __shared__ float x1t[D_ * XS];
    __shared__ float normp[4][64];

    const int tid = threadIdx.x;
    const int b   = blockIdx.y;
    const int n0  = blockIdx.x * 64;

    for (int idx = tid; idx < D_ * 16; idx += 256) {
        int row = idx >> 4, c4 = (idx & 15) * 4;
        float4 a = *(const float4*)(vol0 + ((size_t)(b * D_ + row)) * N_ + n0 + c4);
        float4 c = *(const float4*)(vol1 + ((size_t)(b * D_ + row)) * N_ + n0 + c4);
        *(float4*)(x0t + row * XS + c4) = a;
        *(float4*)(x1t + row * XS + c4) = c;
    }
    __syncthreads();

    const int n  = tid & 63;
    const int og = tid >> 6;
    const int o0 = __builtin_amdgcn_readfirstlane(og * 32);

    const float* WqT = WT;
    const float* WkT = WT + D_ * D_;
    const float* WvT = WT + 2 * D_ * D_;

    float acc[32];

    auto matmul = [&](const float* Wt, const float* xt) {
        #pragma unroll
        for (int j = 0; j < 32; ++j) acc[j] = 0.f;
        for (int d = 0; d < D_; ++d) {
            float xv = xt[d * XS + n];
            const float* wrow = Wt + d * D_ + o0;
            #pragma unroll
            for (int j = 0; j < 32; ++j) acc[j] = fmaf(wrow[j], xv, acc[j]);
        }
        #pragma unroll
        for (int j = 0; j < 32; ++j) acc[j] += xt[(o0 + j) * XS + n];
    };

    auto l2norm_inv = [&]() -> float {
        float ss = 0.f;
        #pragma unroll
        for (int j = 0; j < 32; ++j) ss = fmaf(acc[j], acc[j], ss);
        __syncthreads();
        normp[og][n] = ss;
        __syncthreads();
        float nrm = sqrtf(normp[0][n] + normp[1][n] + normp[2][n] + normp[3][n]);
        return 1.f / fmaxf(nrm, 1e-12f);
    };

    auto store_bf16 = [&](unsigned short* dstbase, float scale) {
        unsigned int pk[16];
        #pragma unroll
        for (int j = 0; j < 16; ++j)
            pk[j] = (unsigned int)f2bf(acc[2 * j] * scale) |
                    ((unsigned int)f2bf(acc[2 * j + 1] * scale) << 16);
        uint4* dst = (uint4*)(dstbase + ((size_t)(n0 + n)) * D_ + o0);
        dst[0] = make_uint4(pk[0],  pk[1],  pk[2],  pk[3]);
        dst[1] = make_uint4(pk[4],  pk[5],  pk[6],  pk[7]);
        dst[2] = make_uint4(pk[8],  pk[9],  pk[10], pk[11]);
        dst[3] = make_uint4(pk[12], pk[13], pk[14], pk[15]);
    };

    auto spill_to = [&](float* xt) {
        __syncthreads();
        #pragma unroll
        for (int j = 0; j < 32; ++j) xt[(o0 + j) * XS + n] = acc[j];
        __syncthreads();
    };

    // ---- Q (scaled by log2 e so attn can use v_exp_f32 = exp2 directly) ----
    matmul(WqT, x0t);
    { float r = l2norm_inv(); store_bf16(Qh + (size_t)b * N_ * D_, r * 1.44269504088896f); }
    // ---- K ----
    matmul(WkT, x1t);
    { float r = l2norm_inv(); store_bf16(Kh + (size_t)b * N_ * D_, r); }
    // ---- V1 -> V1T bf16 [b][144][m] ----
    matmul(WvT, x1t);
    spill_to(x1t);
    for (int idx = tid; idx < D_ * 8; idx += 256) {
        int row = idx >> 3, c8 = (idx & 7) * 8;
        const float* src = x1t + row * XS + c8;
        unsigned int w0 = f2bf(src[0]) | ((unsigned int)f2bf(src[1]) << 16);
        unsigned int w1 = f2bf(src[2]) | ((unsigned int)f2bf(src[3]) << 16);
        unsigned int w2 = f2bf(src[4]) | ((unsigned int)f2bf(src[5]) << 16);
        unsigned int w3 = f2bf(src[6]) | ((unsigned int)f2bf(src[7]) << 16);
        *(uint4*)(V1T + (size_t)(b * DPAD + row) * N_ + n0 + c8) = make_uint4(w0, w1, w2, w3);
    }
    // grid rows (128 = u, 129 = v), row 130 = ones (softmax denom), rest 0
    for (int idx = tid; idx < 16 * 64; idx += 256) {
        int row = 128 + (idx >> 6), col = idx & 63;
        int m = n0 + col;
        float val = 0.f;
        if (row == 128)      val = -1.f + (2.f / 63.f) * (float)(m >> 6);
        else if (row == 129) val = -1.f + (2.f / 63.f) * (float)(m & 63);
        else if (row == 130) val = 1.0f;
        V1T[(size_t)(b * DPAD + row) * N_ + m] = f2bf(val);
    }
    // ---- V0 -> out channels 0..127 (fp32) ----
    matmul(WvT, x0t);
    spill_to(x0t);
    for (int idx = tid; idx < D_ * 16; idx += 256) {
        int row = idx >> 4, c4 = (idx & 15) * 4;
        const float* src = x0t + row * XS + c4;
        float4 v; v.x = src[0]; v.y = src[1]; v.z = src[2]; v.w = src[3];
        *(float4*)(out + ((size_t)(b * CH + row)) * N_ + n0 + c4) = v;
    }
}

// ---------------------------------------------------------------------------
// Kernel 3: attention, 2-phase double-buffered LDS staging of K/V per 64-m
// chunk (global_load_lds, swizzled source), one barrier per chunk. P round
// trip is wave-local (lgkmcnt wait, no barrier). Softmax denom comes from
// the ones-row of V via the PV MFMA; scores bounded so no online rescale.
// ---------------------------------------------------------------------------
#define KBUF_B 16384   // 64 rows x 256 B
#define VBUF_B 18432   // 144 rows x 128 B

__global__ __launch_bounds__(256, 2) void attn_kernel(
    const unsigned short* __restrict__ Qh, const unsigned short* __restrict__ Kh,
    const unsigned short* __restrict__ V1T, float* __restrict__ out)
{
    __shared__ __align__(16) union {
        struct { unsigned short K[2][64 * 128]; unsigned short V[2][144 * 64]; } kv;
        struct { float otile[DPAD * 68]; float maxrow[64]; } ep;
    } sm;
    __shared__ __align__(16) unsigned short Pt[4][16 * 72];

    const int tid  = threadIdx.x;
    const int wave = tid >> 6, lane = tid & 63;
    const int l15  = lane & 15, lh = lane >> 4;

    // XCD-contiguous swizzle: each XCD owns one batch's K/V in its L2
    const int bid = blockIdx.x;
    const int swz = (bid & 7) * 64 + (bid >> 3);
    const int b   = swz >> 6;
    const int nb0 = (swz & 63) * 64;
    const int n0  = nb0 + wave * 16;

    // Q fragments (stay in registers for the whole m loop)
    bf8 qf[4];
    const unsigned short* qp = Qh + ((size_t)(b * N_ + n0 + l15)) * D_ + lh * 8;
    #pragma unroll
    for (int dc = 0; dc < 4; ++dc) qf[dc] = *(const bf8*)(qp + dc * 32);

    f4 acc[9];
    #pragma unroll
    for (int dc = 0; dc < 9; ++dc) acc[dc] = (f4){0.f, 0.f, 0.f, 0.f};
    float Mp[4] = {-1e30f, -1e30f, -1e30f, -1e30f};

    const char* Kbytes = (const char*)(Kh + (size_t)b * N_ * D_);
    const char* Vbytes = (const char*)(V1T + (size_t)b * DPAD * N_);
    char* KB = (char*)&sm.kv.K[0][0];
    char* VB = (char*)&sm.kv.V[0][0];
    unsigned short* Pw = &Pt[wave][0];

    // per-lane staging offsets (swizzled GLOBAL source, linear LDS dest)
    unsigned int koffs[4];
    #pragma unroll
    for (int ii = 0; ii < 4; ++ii) {
        int iss = wave * 4 + ii;
        int drow = iss * 4 + (lane >> 4);
        unsigned int dcol = (unsigned int)((lane & 15) * 16);
        koffs[ii] = (unsigned int)(drow * 256) + (dcol ^ (unsigned int)((drow & 7) << 4));
    }
    unsigned int voffs[5];
    #pragma unroll
    for (int j = 0; j < 5; ++j) {
        int iss = wave + 4 * j;
        int vrow = iss * 8 + (lane >> 3);
        unsigned int dcol = (unsigned int)((lane & 7) * 16);
        voffs[j] = (unsigned int)(vrow * 8192) + (dcol ^ (unsigned int)(((lane >> 3) & 7) << 4));
    }

    auto stage = [&](int bufsel, int t) {
        const char* ksrc = Kbytes + (size_t)t * KBUF_B;
        char* kdst = KB + bufsel * KBUF_B + wave * 4096;
        #pragma unroll
        for (int ii = 0; ii < 4; ++ii) gll16(ksrc + koffs[ii], kdst + ii * 1024);
        const char* vsrc = Vbytes + (size_t)t * 128;
        char* vdst = VB + bufsel * VBUF_B;
        #pragma unroll
        for (int j = 0; j < 5; ++j) {
            int iss = wave + 4 * j;
            if (iss < 18) gll16(vsrc + voffs[j], vdst + iss * 1024);
        }
    };

    const unsigned int xk = (unsigned int)((l15 & 7) << 4);
    unsigned int kxor[4], vxor[2];
    #pragma unroll
    for (int dc = 0; dc < 4; ++dc) kxor[dc] = ((unsigned int)(dc * 64 + lh * 16)) ^ xk;
    #pragma unroll
    for (int ss = 0; ss < 2; ++ss) vxor[ss] = ((unsigned int)(ss * 64 + lh * 16)) ^ xk;

    stage(0, 0);
    __syncthreads();

    for (int t = 0; t < 64; ++t) {
        const int cur = t & 1;
        if (t + 1 < 64) stage(cur ^ 1, t + 1);   // async prefetch next chunk

        const char* Kc = KB + cur * KBUF_B + l15 * 256;
        const char* Vc = VB + cur * VBUF_B + l15 * 128;

        // QK^T: S tile 16 q-rows x 64 m-cols
        f4 sf[4];
        #pragma unroll
        for (int s = 0; s < 4; ++s) sf[s] = (f4){0.f, 0.f, 0.f, 0.f};
        #pragma unroll
        for (int dc = 0; dc < 4; ++dc) {
            const char* ka = Kc + kxor[dc];
            #pragma unroll
            for (int s = 0; s < 4; ++s) {
                bf8 kf = *(const bf8*)(ka + s * 4096);
                sf[s] = __builtin_amdgcn_mfma_f32_16x16x32_bf16(qf[dc], kf, sf[s], 0, 0, 0);
            }
        }
        // p = exp2(s') (Q pre-scaled by log2 e); truncation-round to bf16
        #pragma unroll
        for (int s = 0; s < 4; ++s)
            #pragma unroll
            for (int r = 0; r < 4; ++r) {
                float sv = sf[s][r];
                Mp[r] = fmaxf(Mp[r], sv);
                float p = __builtin_amdgcn_exp2f(sv);
                Pw[(lh * 4 + r) * 72 + s * 16 + l15] =
                    (unsigned short)(__float_as_uint(p) >> 16);
            }
        asm volatile("s_waitcnt lgkmcnt(0)" ::: "memory");   // wave-local P order
        __builtin_amdgcn_sched_barrier(0);
        // PV over 144 padded channels (row 130 of V = ones -> denominator)
        #pragma unroll
        for (int ss = 0; ss < 2; ++ss) {
            bf8 pf = *(const bf8*)((const char*)Pw + l15 * 144 + lh * 16 + ss * 64);
            #pragma unroll
            for (int dc = 0; dc < 9; ++dc) {
                bf8 vf = *(const bf8*)(Vc + vxor[ss] + dc * 2048);
                acc[dc] = __builtin_amdgcn_mfma_f32_16x16x32_bf16(pf, vf, acc[dc], 0, 0, 0);
            }
        }
        __syncthreads();   // staged loads landed; all reads of old buffer done
    }

    // denominator from the ones-row (channel 130 -> dc=8, l15=2)
    float rl[4];
    #pragma unroll
    for (int r = 0; r < 4; ++r) {
        float lsum = __shfl(acc[8][r], (lane & 48) + 2, 64);
        rl[r] = 1.0f / lsum;
    }
    #pragma unroll
    for (int off = 1; off < 16; off <<= 1)
        #pragma unroll
        for (int r = 0; r < 4; ++r)
            Mp[r] = fmaxf(Mp[r], __shfl_xor(Mp[r], off, 64));

    // epilogue: transpose through LDS (aliases K/V buffers; loop is done)
    #pragma unroll
    for (int dc = 0; dc < 9; ++dc)
        #pragma unroll
        for (int r = 0; r < 4; ++r)
            sm.ep.otile[(dc * 16 + l15) * 68 + wave * 16 + lh * 4 + r] = acc[dc][r] * rl[r];
    if (l15 == 0) {
        #pragma unroll
        for (int r = 0; r < 4; ++r)
            sm.ep.maxrow[wave * 16 + lh * 4 + r] = __builtin_amdgcn_exp2f(Mp[r]) * rl[r];
    }
    __syncthreads();
    for (int idx = tid; idx < 130 * 16; idx += 256) {
        int row = idx >> 4, c4 = (idx & 15) * 4;
        int ch = (row < 128) ? (128 + row) : (256 + (row - 128));
        const float* src = sm.ep.otile + row * 68 + c4;
        float4 v; v.x = src[0]; v.y = src[1]; v.z = src[2]; v.w = src[3];
        *(float4*)(out + ((size_t)(b * CH + ch)) * N_ + nb0 + c4) = v;
    }
    if (tid < 16) {
        float4 v;
        v.x = sm.ep.maxrow[tid * 4];     v.y = sm.ep.maxrow[tid * 4 + 1];
        v.z = sm.ep.maxrow[tid * 4 + 2]; v.w = sm.ep.maxrow[tid * 4 + 3];
        *(float4*)(out + ((size_t)(b * CH + 258)) * N_ + nb0 + tid * 4) = v;
    }
}

// ---------------------------------------------------------------------------
extern "C" void kernel_launch(void* const* d_in, const int* in_sizes, int n_in,
                              void* d_out, int out_size, void* d_ws, size_t ws_size,
                              hipStream_t stream) {
    const float* vol0 = (const float*)d_in[0];
    const float* vol1 = (const float*)d_in[1];
    const float* Wq   = (const float*)d_in[2];
    const float* Wk   = (const float*)d_in[3];
    const float* Wv   = (const float*)d_in[4];
    float* out = (float*)d_out;

    char* ws = (char*)d_ws;
    const size_t QH_BYTES  = (size_t)B_ * N_ * D_ * 2;
    const size_t V1T_BYTES = (size_t)B_ * DPAD * N_ * 2;
    unsigned short* Qh  = (unsigned short*)(ws);
    unsigned short* Kh  = (unsigned short*)(ws + QH_BYTES);
    unsigned short* V1T = (unsigned short*)(ws + 2 * QH_BYTES);
    float* WT = (float*)(ws + 2 * QH_BYTES + V1T_BYTES);

    hipLaunchKernelGGL(wtrans_kernel, dim3(3), dim3(256), 0, stream, Wq, Wk, Wv, WT);
    hipLaunchKernelGGL(proj_kernel, dim3(64, B_), dim3(256), 0, stream,
                       vol0, vol1, WT, out, Qh, Kh, V1T);
    hipLaunchKernelGGL(attn_kernel, dim3(512), dim3(256), 0, stream,
                       Qh, Kh, V1T, out);
}

// Round 3
// 161.497 us; speedup vs baseline: 4.3997x; 1.4150x over previous
//
#include <hip/hip_runtime.h>
#include <hip/hip_bf16.h>

// Problem constants (B, D, H, W) = (8, 128, 64, 64)
#define B_   8
#define D_   128
#define N_   4096
#define CH   259            // 2D+3 output channels
#define DPAD 144            // v1 channels padded: 128 v1 + 2 grid + row130=ones + garbage pad

typedef short bf8 __attribute__((ext_vector_type(8)));   // 8 bf16 (MFMA A/B frag)
typedef float f4  __attribute__((ext_vector_type(4)));   // MFMA C/D frag

typedef unsigned int as1_u32 __attribute__((address_space(1)));
typedef unsigned int as3_u32 __attribute__((address_space(3)));

__device__ __forceinline__ void gll16(const void* g, void* l) {
    // async global->LDS, 16B/lane; LDS dest = wave-uniform base + lane*16
    __builtin_amdgcn_global_load_lds((as1_u32*)(unsigned long long)g,
                                     (as3_u32*)(unsigned int)(unsigned long long)l,
                                     16, 0, 0);
}

__device__ __forceinline__ unsigned short f2bf(float x) {
    unsigned int u = __float_as_uint(x);
    return (unsigned short)((u + 0x7FFFu + ((u >> 16) & 1u)) >> 16);
}

__device__ __forceinline__ unsigned int cvtpk(float lo, float hi) {
    unsigned int r;
    asm("v_cvt_pk_bf16_f32 %0, %1, %2" : "=v"(r) : "v"(lo), "v"(hi));
    return r;
}

// ---------------------------------------------------------------------------
// Kernel 1: W fp32 -> bf16 (RNE), layout [3][o][d] (row-major, as input)
// ---------------------------------------------------------------------------
__global__ void wconv_kernel(const float* __restrict__ Wq,
                             const float* __restrict__ Wk,
                             const float* __restrict__ Wv,
                             unsigned short* __restrict__ Wb) {
    const float* src = (blockIdx.x == 0) ? Wq : (blockIdx.x == 1) ? Wk : Wv;
    unsigned short* dst = Wb + (size_t)blockIdx.x * D_ * D_;
    for (int i = threadIdx.x; i < D_ * D_; i += blockDim.x) dst[i] = f2bf(src[i]);
}

// ---------------------------------------------------------------------------
// Kernel 2: MFMA projections + residual + L2 norm, fused x-transpose.
// Block = (b, 64-n tile). C[n][o] = mfma(A = x^T-frag, B = W-frag) per output.
//   Qp   bf16 [b][o][n]  o-major, pre-scaled by log2(e)/||q||   (attn gathers)
//   Kh   bf16 [b][m][128] m-major (for attn gll16 staging)
//   V1T  bf16 [b][144][m] rows 128/129 grid, 130 ones
//   v0   fp32 -> out channels 0..127
// ---------------------------------------------------------------------------
__global__ __launch_bounds__(256, 2) void proj_kernel(
    const float* __restrict__ vol0, const float* __restrict__ vol1,
    const unsigned short* __restrict__ Wb, float* __restrict__ out,
    unsigned short* __restrict__ Qp, unsigned short* __restrict__ Kh,
    unsigned short* __restrict__ V1T)
{
    __shared__ __align__(16) float xs[2][D_ * 64];   // [arr][d][64 n], 256B rows, col-swizzled

    const int tid  = threadIdx.x;
    const int wave = tid >> 6, lane = tid & 63;
    const int l15  = lane & 15, lh = lane >> 4;

    const int bid = blockIdx.x;
    const int swz = (bid & 7) * 64 + (bid >> 3);     // XCD b owns batch b
    const int b   = swz >> 6;
    const int nt  = swz & 63;
    const int n0  = nt * 64;

    // ---- stage x0/x1 fp32 tiles [128 d][64 n], source col-swizzled ----
    #pragma unroll
    for (int a = 0; a < 2; ++a) {
        const char* src = (const char*)((a ? vol1 : vol0) + (size_t)b * D_ * N_ + n0);
        char* dstb = (char*)&xs[a][0];
        #pragma unroll
        for (int i = 0; i < 8; ++i) {
            int dst16 = i * 4096 + tid * 16;
            int row = dst16 >> 8, cb = dst16 & 255;
            gll16(src + (size_t)row * (N_ * 4) + (cb ^ (((row >> 3) & 7) << 4)), dstb + dst16);
        }
    }
    __syncthreads();

    const int nrow = wave * 16 + l15;    // n-row this lane supplies to A-frags

    auto afrag = [&](const float* base, int k) -> bf8 {
        const int dbase = k * 32 + lh * 8;
        const unsigned int cb = ((unsigned int)(nrow * 4)) ^ (((unsigned int)((k * 4 + lh) & 7)) << 4);
        const float* p = base + dbase * 64 + (cb >> 2);
        union { bf8 v; unsigned int w[4]; } u;
        #pragma unroll
        for (int jj = 0; jj < 4; ++jj)
            u.w[jj] = cvtpk(p[(2 * jj) * 64], p[(2 * jj + 1) * 64]);
        return u.v;
    };

    f4 aq[8], ak[8], a0v[8], a1v[8];
    #pragma unroll
    for (int ob = 0; ob < 8; ++ob) {
        aq[ob] = (f4){0.f,0.f,0.f,0.f}; ak[ob] = (f4){0.f,0.f,0.f,0.f};
        a0v[ob] = (f4){0.f,0.f,0.f,0.f}; a1v[ob] = (f4){0.f,0.f,0.f,0.f};
    }

    const unsigned short* Wqb = Wb;
    const unsigned short* Wkb = Wb + D_ * D_;
    const unsigned short* Wvb = Wb + 2 * D_ * D_;

    for (int k = 0; k < 4; ++k) {
        bf8 x0f = afrag(&xs[0][0], k);
        bf8 x1f = afrag(&xs[1][0], k);
        #pragma unroll
        for (int ob = 0; ob < 8; ++ob) {
            const size_t woff = ((size_t)(ob * 16 + l15)) * D_ + k * 32 + lh * 8;
            bf8 wq = *(const bf8*)(Wqb + woff);
            bf8 wk = *(const bf8*)(Wkb + woff);
            bf8 wv = *(const bf8*)(Wvb + woff);
            aq[ob]  = __builtin_amdgcn_mfma_f32_16x16x32_bf16(x0f, wq, aq[ob], 0, 0, 0);
            ak[ob]  = __builtin_amdgcn_mfma_f32_16x16x32_bf16(x1f, wk, ak[ob], 0, 0, 0);
            a0v[ob] = __builtin_amdgcn_mfma_f32_16x16x32_bf16(x0f, wv, a0v[ob], 0, 0, 0);
            a1v[ob] = __builtin_amdgcn_mfma_f32_16x16x32_bf16(x1f, wv, a1v[ob], 0, 0, 0);
        }
    }

    // ---- residual (from staged tile) + norm partials ----
    float ssq[4] = {0.f,0.f,0.f,0.f}, ssk[4] = {0.f,0.f,0.f,0.f};
    #pragma unroll
    for (int ob = 0; ob < 8; ++ob) {
        const int o = ob * 16 + l15;
        const unsigned int okey = (((unsigned int)((o >> 3) & 7)) << 4);
        #pragma unroll
        for (int r = 0; r < 4; ++r) {
            int n = wave * 16 + lh * 4 + r;
            int ci = o * 64 + (int)(((((unsigned int)(n * 4)) ^ okey) >> 2));
            float r0 = xs[0][ci], r1 = xs[1][ci];
            aq[ob][r] += r0; ak[ob][r] += r1; a0v[ob][r] += r0; a1v[ob][r] += r1;
            ssq[r] = fmaf(aq[ob][r], aq[ob][r], ssq[r]);
            ssk[r] = fmaf(ak[ob][r], ak[ob][r], ssk[r]);
        }
    }
    #pragma unroll
    for (int off = 1; off < 16; off <<= 1)
        #pragma unroll
        for (int r = 0; r < 4; ++r) {
            ssq[r] += __shfl_xor(ssq[r], off, 64);
            ssk[r] += __shfl_xor(ssk[r], off, 64);
        }
    float rq[4], rk[4];
    #pragma unroll
    for (int r = 0; r < 4; ++r) {
        rq[r] = 1.44269504088896f / fmaxf(sqrtf(ssq[r]), 1e-12f);  // fold log2(e) into Q
        rk[r] = 1.0f / fmaxf(sqrtf(ssk[r]), 1e-12f);
    }

    // ---- direct stores: v0 (fp32), V1T (bf16), Qp (bf16, o-major) ----
    const int nbase = n0 + wave * 16 + lh * 4;
    #pragma unroll
    for (int ob = 0; ob < 8; ++ob) {
        const int o = ob * 16 + l15;
        *(f4*)(out + ((size_t)(b * CH + o)) * N_ + nbase) = a0v[ob];
        uint2 pv; pv.x = cvtpk(a1v[ob][0], a1v[ob][1]); pv.y = cvtpk(a1v[ob][2], a1v[ob][3]);
        *(uint2*)(V1T + ((size_t)(b * DPAD + o)) * N_ + nbase) = pv;
        uint2 pq; pq.x = cvtpk(aq[ob][0]*rq[0], aq[ob][1]*rq[1]);
        pq.y = cvtpk(aq[ob][2]*rq[2], aq[ob][3]*rq[3]);
        *(uint2*)(Qp + ((size_t)(b * D_ + o)) * N_ + nbase) = pq;
    }
    // grid rows 128/129 + ones row 130
    if (tid < 192) {
        int row = 128 + (tid >> 6), col = tid & 63;
        int m = n0 + col;
        float val = (row == 128) ? (-1.f + (2.f / 63.f) * (float)(m >> 6))
                  : (row == 129) ? (-1.f + (2.f / 63.f) * (float)(m & 63)) : 1.0f;
        V1T[((size_t)(b * DPAD + row)) * N_ + m] = f2bf(val);
    }

    // ---- Kh: per-wave LDS transpose chunk (x tiles dead after barrier) ----
    __syncthreads();
    float* chunk = &xs[0][0] + wave * 2176;          // [128 o][17] fp32 per wave
    #pragma unroll
    for (int ob = 0; ob < 8; ++ob) {
        const int o = ob * 16 + l15;
        #pragma unroll
        for (int r = 0; r < 4; ++r) chunk[o * 17 + lh * 4 + r] = ak[ob][r] * rk[r];
    }
    asm volatile("s_waitcnt lgkmcnt(0)" ::: "memory");
    __builtin_amdgcn_sched_barrier(0);
    {
        const int o0 = (lane & 15) * 8, nr = lane >> 4;
        #pragma unroll
        for (int t = 0; t < 4; ++t) {
            int nl = t * 4 + nr;
            float f[8];
            #pragma unroll
            for (int j = 0; j < 8; ++j) f[j] = chunk[(o0 + j) * 17 + nl];
            uint4 st;
            st.x = cvtpk(f[0], f[1]); st.y = cvtpk(f[2], f[3]);
            st.z = cvtpk(f[4], f[5]); st.w = cvtpk(f[6], f[7]);
            *(uint4*)(Kh + ((size_t)(b * N_ + n0 + wave * 16 + nl)) * D_ + o0) = st;
        }
    }
}

// ---------------------------------------------------------------------------
// Kernel 3: attention. Swapped QK^T (mfma(K,Q)) puts each lane's S values at
// consecutive m for fixed n=l15 -> P written as [16 n][64 m] with cvt_pk b64
// (XOR-swizzled rows), read back as one b128 A-frag. Denominator = ones-row
// of V via PV MFMA; max via per-lane scalar. One barrier per 64-m chunk,
// double-buffered K/V staging via global_load_lds with swizzled source.
// ---------------------------------------------------------------------------
#define KBUF_B 16384   // 64 rows x 256 B
#define VBUF_B 18432   // 144 rows x 128 B

__global__ __launch_bounds__(256, 2) void attn_kernel(
    const unsigned short* __restrict__ Qp, const unsigned short* __restrict__ Kh,
    const unsigned short* __restrict__ V1T, float* __restrict__ out)
{
    __shared__ __align__(16) union {
        struct { unsigned short K[2][64 * 128]; unsigned short V[2][144 * 64]; } kv;
        struct { float otile[DPAD * 68]; } ep;
    } sm;
    __shared__ __align__(16) unsigned short Pt[4][16 * 64];   // per-wave P[16 n][64 m]

    const int tid  = threadIdx.x;
    const int wave = tid >> 6, lane = tid & 63;
    const int l15  = lane & 15, lh = lane >> 4;

    const int bid = blockIdx.x;
    const int swz = (bid & 7) * 64 + (bid >> 3);
    const int b   = swz >> 6;
    const int nb0 = (swz & 63) * 64;
    const int n0  = nb0 + wave * 16;

    // one-time Q gather from o-major Qp (already scaled by log2e/||q||)
    bf8 qf[4];
    const unsigned short* Qb = Qp + (size_t)b * D_ * N_;
    #pragma unroll
    for (int dc = 0; dc < 4; ++dc) {
        union { bf8 v; unsigned short e[8]; } u;
        #pragma unroll
        for (int j = 0; j < 8; ++j)
            u.e[j] = Qb[((size_t)(dc * 32 + lh * 8 + j)) * N_ + n0 + l15];
        qf[dc] = u.v;
    }

    f4 acc[9];
    #pragma unroll
    for (int dc = 0; dc < 9; ++dc) acc[dc] = (f4){0.f, 0.f, 0.f, 0.f};
    float Mp = -1e30f;

    const char* Kbytes = (const char*)(Kh + (size_t)b * N_ * D_);
    const char* Vbytes = (const char*)(V1T + (size_t)b * DPAD * N_);
    char* KB = (char*)&sm.kv.K[0][0];
    char* VB = (char*)&sm.kv.V[0][0];
    char* Pw = (char*)&Pt[wave][0];

    unsigned int koffs[4];
    #pragma unroll
    for (int ii = 0; ii < 4; ++ii) {
        int iss = wave * 4 + ii;
        int drow = iss * 4 + (lane >> 4);
        unsigned int dcol = (unsigned int)((lane & 15) * 16);
        koffs[ii] = (unsigned int)(drow * 256) + (dcol ^ (unsigned int)((drow & 7) << 4));
    }
    unsigned int voffs[5];
    #pragma unroll
    for (int j = 0; j < 5; ++j) {
        int iss = wave + 4 * j;
        int vrow = iss * 8 + (lane >> 3);
        unsigned int dcol = (unsigned int)((lane & 7) * 16);
        voffs[j] = (unsigned int)(vrow * 8192) + (dcol ^ (unsigned int)(((lane >> 3) & 7) << 4));
    }

    auto stage = [&](int bufsel, int t) {
        const char* ksrc = Kbytes + (size_t)t * KBUF_B;
        char* kdst = KB + bufsel * KBUF_B + wave * 4096;
        #pragma unroll
        for (int ii = 0; ii < 4; ++ii) gll16(ksrc + koffs[ii], kdst + ii * 1024);
        const char* vsrc = Vbytes + (size_t)t * 128;
        char* vdst = VB + bufsel * VBUF_B;
        #pragma unroll
        for (int j = 0; j < 5; ++j) {
            int iss = wave + 4 * j;
            if (iss < 18) gll16(vsrc + voffs[j], vdst + iss * 1024);
        }
    };

    const unsigned int xk = (unsigned int)((l15 & 7) << 4);
    unsigned int kxor[4], vxor[2];
    #pragma unroll
    for (int dc = 0; dc < 4; ++dc) kxor[dc] = ((unsigned int)(dc * 64 + lh * 16)) ^ xk;
    #pragma unroll
    for (int ss = 0; ss < 2; ++ss) vxor[ss] = ((unsigned int)(ss * 64 + lh * 16)) ^ xk;
    const unsigned int pswz = (unsigned int)((l15 & 7) << 4);

    stage(0, 0);
    __syncthreads();

    for (int t = 0; t < 64; ++t) {
        const int cur = t & 1;
        if (t + 1 < 64) stage(cur ^ 1, t + 1);

        const char* Kc = KB + cur * KBUF_B + l15 * 256;
        const char* Vc = VB + cur * VBUF_B + l15 * 128;

        // QK^T swapped: sf[s] = S^T tile; lane holds m = s*16+lh*4+r, n = l15
        f4 sf[4];
        #pragma unroll
        for (int s = 0; s < 4; ++s) sf[s] = (f4){0.f, 0.f, 0.f, 0.f};
        #pragma unroll
        for (int dc = 0; dc < 4; ++dc) {
            const char* ka = Kc + kxor[dc];
            #pragma unroll
            for (int s = 0; s < 4; ++s) {
                bf8 kf = *(const bf8*)(ka + s * 4096);
                sf[s] = __builtin_amdgcn_mfma_f32_16x16x32_bf16(kf, qf[dc], sf[s], 0, 0, 0);
            }
        }
        // p = exp2(s'); pack 4 consecutive-m bf16 -> one b64 swizzled write
        #pragma unroll
        for (int s = 0; s < 4; ++s) {
            float p0 = __builtin_amdgcn_exp2f(sf[s][0]);
            float p1 = __builtin_amdgcn_exp2f(sf[s][1]);
            float p2 = __builtin_amdgcn_exp2f(sf[s][2]);
            float p3 = __builtin_amdgcn_exp2f(sf[s][3]);
            Mp = fmaxf(Mp, fmaxf(fmaxf(sf[s][0], sf[s][1]), fmaxf(sf[s][2], sf[s][3])));
            uint2 w; w.x = cvtpk(p0, p1); w.y = cvtpk(p2, p3);
            *(uint2*)(Pw + l15 * 128 + (((unsigned int)(s * 32 + lh * 8)) ^ pswz)) = w;
        }
        asm volatile("s_waitcnt lgkmcnt(0)" ::: "memory");
        __builtin_amdgcn_sched_barrier(0);
        // PV over 144 padded channels (ones-row 130 -> denominator)
        #pragma unroll
        for (int ss = 0; ss < 2; ++ss) {
            bf8 pf = *(const bf8*)(Pw + l15 * 128 + (((unsigned int)(ss * 64 + lh * 16)) ^ pswz));
            #pragma unroll
            for (int dc = 0; dc < 9; ++dc) {
                bf8 vf = *(const bf8*)(Vc + vxor[ss] + dc * 2048);
                acc[dc] = __builtin_amdgcn_mfma_f32_16x16x32_bf16(pf, vf, acc[dc], 0, 0, 0);
            }
        }
        __syncthreads();
    }

    // denominator from ones-row (ch 130 -> dc=8, l15=2)
    float rl[4];
    #pragma unroll
    for (int r = 0; r < 4; ++r)
        rl[r] = 1.0f / __shfl(acc[8][r], (lane & 48) + 2, 64);
    // max over m: lane covers n=l15 subset; combine over lh groups
    Mp = fmaxf(Mp, __shfl_xor(Mp, 16, 64));
    Mp = fmaxf(Mp, __shfl_xor(Mp, 32, 64));
    float me = __builtin_amdgcn_exp2f(Mp);

    // epilogue transpose via LDS (aliases K/V buffers)
    #pragma unroll
    for (int dc = 0; dc < 9; ++dc)
        #pragma unroll
        for (int r = 0; r < 4; ++r)
            sm.ep.otile[(dc * 16 + l15) * 68 + wave * 16 + lh * 4 + r] = acc[dc][r] * rl[r];
    // max-score channel -> otile row 130 (overwrites denominator channel)
    #pragma unroll
    for (int r = 0; r < 4; ++r) {
        float ms = __shfl(me, (lane & 48) + lh * 4 + r, 64) * rl[r];
        if (l15 == 0) sm.ep.otile[130 * 68 + wave * 16 + lh * 4 + r] = ms;
    }
    __syncthreads();
    for (int idx = tid; idx < 131 * 16; idx += 256) {
        int row = idx >> 4, c4 = (idx & 15) * 4;
        int ch = (row < 128) ? (128 + row) : (256 + (row - 128));
        const float* src = sm.ep.otile + row * 68 + c4;
        float4 v; v.x = src[0]; v.y = src[1]; v.z = src[2]; v.w = src[3];
        *(float4*)(out + ((size_t)(b * CH + ch)) * N_ + nb0 + c4) = v;
    }
}

// ---------------------------------------------------------------------------
extern "C" void kernel_launch(void* const* d_in, const int* in_sizes, int n_in,
                              void* d_out, int out_size, void* d_ws, size_t ws_size,
                              hipStream_t stream) {
    const float* vol0 = (const float*)d_in[0];
    const float* vol1 = (const float*)d_in[1];
    const float* Wq   = (const float*)d_in[2];
    const float* Wk   = (const float*)d_in[3];
    const float* Wv   = (const float*)d_in[4];
    float* out = (float*)d_out;

    char* ws = (char*)d_ws;
    const size_t QP_BYTES  = (size_t)B_ * D_ * N_ * 2;     // 8 MiB, [b][o][n]
    const size_t KH_BYTES  = (size_t)B_ * N_ * D_ * 2;     // 8 MiB, [b][m][d]
    const size_t V1T_BYTES = (size_t)B_ * DPAD * N_ * 2;   // 9 MiB, [b][ch][m]
    unsigned short* Qp  = (unsigned short*)(ws);
    unsigned short* Kh  = (unsigned short*)(ws + QP_BYTES);
    unsigned short* V1T = (unsigned short*)(ws + QP_BYTES + KH_BYTES);
    unsigned short* Wb  = (unsigned short*)(ws + QP_BYTES + KH_BYTES + V1T_BYTES);

    hipLaunchKernelGGL(wconv_kernel, dim3(3), dim3(256), 0, stream, Wq, Wk, Wv, Wb);
    hipLaunchKernelGGL(proj_kernel, dim3(512), dim3(256), 0, stream,
                       vol0, vol1, Wb, out, Qp, Kh, V1T);
    hipLaunchKernelGGL(attn_kernel, dim3(512), dim3(256), 0, stream,
                       Qp, Kh, V1T, out);
}